// Round 7
// baseline (1099.318 us; speedup 1.0000x reference)
//
#include <hip/hip_runtime.h>

#define SEQ   120
#define WARM  96
#define FLEN  24
#define HDIM  256

typedef __attribute__((ext_vector_type(8))) short bf16x8;
typedef __attribute__((ext_vector_type(4))) float floatx4;
typedef unsigned int uint;
typedef unsigned long long ull;

// ws layout (bytes):
//   WHI [0,512K)   bf16 frag-linear W-hi: tile=(s*8+uch8*2+gpair), sidx=((tile*8+kt)*64+lane)*8+j
//   WLO [512K,1M)  same layout
//   BB  [1M,+4K)   f32 b_ih+b_hh ; WI [1M+4K,+4K) f32 W_ih col
//   BAR [1M+8K,+16K)  uint flag[64], stride 64 uints
//   HG  [BAR+16K,+4M) uint h packed (hi<<16|lo): 2 parities x 64 rg x 8192
//   XT  [HG+4M,+960K) f32 x transposed [t][row]
#define WHI_OFF 0
#define WLO_OFF (512 * 1024)
#define BB_OFF  (1024 * 1024)
#define WI_OFF  (1024 * 1024 + 4096)
#define BAR_OFF (1024 * 1024 + 8192)
#define HG_OFF  (BAR_OFF + 16384)
#define HG_PAR  524288
#define XT_OFF  (HG_OFF + 4 * 1024 * 1024)

#define LDS_BYTES 131712   // wlo 64K | hbuf 2x32K | y 512B | mb 16B (+pad)

__device__ __forceinline__ short f2bf(float v) {
    unsigned u = __float_as_uint(v);
    u += 0x7FFF + ((u >> 16) & 1);              // RNE
    return (short)(u >> 16);
}
__device__ __forceinline__ float bf2f(short s) {
    return __uint_as_float(((unsigned)(unsigned short)s) << 16);
}
__device__ __forceinline__ float fast_sig(float x) {
    return 1.0f / (1.0f + __expf(-x));
}
__device__ __forceinline__ float fast_tanh(float x) {
    return 1.0f - 2.0f / (__expf(2.0f * x) + 1.0f);
}
__device__ __forceinline__ ull load_llc64(const ull* p) {
    return __hip_atomic_load(p, __ATOMIC_RELAXED, __HIP_MEMORY_SCOPE_AGENT);
}
__device__ __forceinline__ void store_llc32(uint* p, uint v) {
    __hip_atomic_store(p, v, __ATOMIC_RELAXED, __HIP_MEMORY_SCOPE_AGENT);
}

__global__ __launch_bounds__(256) void lstm_prep(
    const float* __restrict__ W_ih, const float* __restrict__ W_hh,
    const float* __restrict__ b_ih, const float* __restrict__ b_hh,
    const float* __restrict__ h0, const float* __restrict__ x,
    unsigned char* __restrict__ ws)
{
    int tid = blockIdx.x * 256 + threadIdx.x;        // grid 2048*256
    if (tid < 262144) {
        int row4h = tid >> 8, k = tid & 255;
        float v = W_hh[tid];
        short hi = f2bf(v), lo = f2bf(v - bf2f(hi));
        int gate = row4h >> 8, unit = row4h & 255;
        int s = unit >> 5, uin = unit & 31;
        int tile = s * 8 + (uin >> 3) * 2 + (gate >> 1);
        int lane_f = ((uin & 7) * 2 + (gate & 1)) + 16 * ((k >> 3) & 3);
        size_t sidx = ((size_t)(tile * 8 + (k >> 5)) * 64 + lane_f) * 8 + (k & 7);
        ((short*)(ws + WHI_OFF))[sidx] = hi;
        ((short*)(ws + WLO_OFF))[sidx] = lo;
    }
    if (tid < 524288) {                               // h0 -> parity 0
        int row = tid >> 8, k = tid & 255;
        float v = h0[tid];
        short hi = f2bf(v), lo = f2bf(v - bf2f(hi));
        int rg = row >> 5, rt = (row >> 4) & 1, m = row & 15;
        size_t uidx = (size_t)rg * 8192 +
            ((size_t)(rt * 8 + (k >> 5)) * 64 + m + 16 * ((k >> 3) & 3)) * 8 + (k & 7);
        ((uint*)(ws + HG_OFF))[uidx] =
            ((uint)(unsigned short)hi << 16) | (uint)(unsigned short)lo;
    }
    if (tid < 2048 * SEQ) {                           // x -> [t][row]
        int row = tid / SEQ, tt = tid % SEQ;
        ((float*)(ws + XT_OFF))[tt * 2048 + row] = x[tid];
    }
    if (tid < 1024) {
        ((float*)(ws + BB_OFF))[tid] = b_ih[tid] + b_hh[tid];
        ((float*)(ws + WI_OFF))[tid] = W_ih[tid];
    }
    if (tid < 64) ((uint*)(ws + BAR_OFF))[tid * 64] = 0u;
}

__global__ void __launch_bounds__(512, 1) lstm_main(
    const float* __restrict__ c0, unsigned char* __restrict__ ws,
    const float* __restrict__ fcw, const float* __restrict__ fcb,
    float* __restrict__ out)
{
    extern __shared__ char smem[];
    short* wlo_s = (short*)smem;                      // 64 KB, shared by halves

    const int tid  = threadIdx.x;
    const int half = tid >> 8;                        // 0: waves 0-3, 1: waves 4-7
    const int ht   = tid & 255;
    const int wl   = (tid >> 6) & 3;                  // wave in half
    const int lane = tid & 63;
    const int quad = lane >> 4, nof = lane & 15;
    const int rt   = wl & 1, uchw = wl >> 1;
    const int blk  = blockIdx.x;
    const int s    = blk >> 5;                        // unit-slice (32 units)
    const int rg   = ((blk & 31) << 1) + half;        // row-group (32 rows)

    short* hhi_s = (short*)(smem + 65536 + half * 32768);   // 8192 shorts
    short* hlo_s = hhi_s + 8192;
    float* y_s   = (float*)(smem + 131072) + half * 64;     // [par][32]
    uint*  mb    = (uint*)(smem + 131584) + half * 2;       // {stage, done}

    const float* bb = (const float*)(ws + BB_OFF);
    const float* wi = (const float*)(ws + WI_OFF);
    const float* xT = (const float*)(ws + XT_OFF);
    uint* hg   = (uint*)(ws + HG_OFF);
    uint* barp = (uint*)(ws + BAR_OFF) + rg * 64;

    // ---- W-lo slice -> LDS (once) ----
    {
        const uint4* srcw = (const uint4*)(ws + WLO_OFF) + (size_t)s * 4096;
        uint4* dstw = (uint4*)wlo_s;
        for (int i = tid; i < 4096; i += 512) dstw[i] = srcw[i];
    }
    // ---- W-hi fragments -> regs (4 n-tiles x 8 kt) ----
    bf16x8 bhi[4][8];
    {
        const bf16x8* whif = (const bf16x8*)(ws + WHI_OFF);
        #pragma unroll
        for (int nt = 0; nt < 4; ++nt)
            #pragma unroll
            for (int kt = 0; kt < 8; ++kt)
                bhi[nt][kt] = whif[(size_t)((s * 8 + uchw * 4 + nt) * 8 + kt) * 64 + lane];
    }

    // ---- per-thread constants ----
    const int ug = s * 32 + uchw * 16 + ((lane & 1) << 3) + (nof >> 1);  // owned unit
    float bbg[4], wig[4];
    #pragma unroll
    for (int g = 0; g < 4; ++g) { bbg[g] = bb[g * 256 + ug]; wig[g] = wi[g * 256 + ug]; }
    const float fcb0 = fcb[0];
    float c[4];
    #pragma unroll
    for (int i = 0; i < 4; ++i)
        c[i] = c0[(rg * 32 + rt * 16 + quad * 4 + i) * HDIM + ug];
    const int ktu = ug >> 5, ksubu = (ug >> 3) & 3, ju = ug & 7;

    if (ht < 64) y_s[ht] = 0.f;
    if (ht < 2)  mb[ht] = 0u;
    __syncthreads();          // last full-block sync

    uint nbar = 0;
    for (int t = 0; t <= SEQ; ++t) {
        nbar += 4;
        const uint par = (uint)t & 1u;
        const uint tgt = 8u * (uint)t;
        while (__hip_atomic_load(barp, __ATOMIC_RELAXED, __HIP_MEMORY_SCOPE_AGENT) < tgt)
            __builtin_amdgcn_s_sleep(1);

        // ---- staging: 32 uints/thread from LLC, chunk ci = ht + 256*g ----
        const ull* hb = (const ull*)(hg + (size_t)par * HG_PAR + (size_t)rg * 8192);
        ull e[16];
        #pragma unroll
        for (int g = 0; g < 4; ++g) {
            const ull* p = hb + (size_t)(ht + 256 * g) * 4;
            e[4 * g + 0] = load_llc64(p + 0);
            e[4 * g + 1] = load_llc64(p + 1);
            e[4 * g + 2] = load_llc64(p + 2);
            e[4 * g + 3] = load_llc64(p + 3);
        }
        float yadd[2] = {0.f, 0.f};
        #pragma unroll
        for (int g = 0; g < 4; ++g) {
            uint4 hi4, lo4;
            uint xs[8];
            #pragma unroll
            for (int q = 0; q < 4; ++q) {
                ull a = e[4 * g + q];
                uint x0 = (uint)a, x1 = (uint)(a >> 32);
                xs[2 * q] = x0; xs[2 * q + 1] = x1;
                ((uint*)&hi4)[q] = (x0 >> 16) | (x1 & 0xFFFF0000u);
                ((uint*)&lo4)[q] = (x0 & 0xFFFFu) | (x1 << 16);
            }
            const int ci = ht + 256 * g;
            *(uint4*)(hhi_s + ci * 8) = hi4;
            *(uint4*)(hlo_s + ci * 8) = lo4;
            if (t >= WARM) {
                const int kb = (((ht >> 6) | ((g & 1) << 2)) << 5) + (((ht >> 4) & 3) << 3);
                float4 fa = *(const float4*)(fcw + kb);
                float4 fb = *(const float4*)(fcw + kb + 4);
                float p = 0.f;
                const float fc8[8] = {fa.x, fa.y, fa.z, fa.w, fb.x, fb.y, fb.z, fb.w};
                #pragma unroll
                for (int j = 0; j < 8; ++j)
                    p = fmaf(fc8[j], __uint_as_float(xs[j] & 0xFFFF0000u) +
                                     __uint_as_float(xs[j] << 16), p);
                yadd[g >> 1] += p;
            }
        }
        if (t >= WARM) {
            atomicAdd(&y_s[par * 32 + (ht & 15)], yadd[0]);
            atomicAdd(&y_s[par * 32 + 16 + (ht & 15)], yadd[1]);
        }

        // ---- mini-barrier: staging writes -> MFMA reads (this half only) ----
        asm volatile("s_waitcnt lgkmcnt(0)" ::: "memory");
        if (lane == 0) atomicAdd(&mb[0], 1u);
        while (*(volatile uint*)&mb[0] < nbar) {}

        if (wl == 1 && lane < 32) y_s[(1u - par) * 32 + lane] = 0.f;  // next parity
        if (t >= WARM + 1 && s == 0 && wl == 0 && lane < 32)
            out[(rg * 32 + lane) * FLEN + (t - WARM - 1)] = y_s[par * 32 + lane] + fcb0;
        if (t == SEQ) break;

        float4 xv = {0.f, 0.f, 0.f, 0.f};
        if (t < WARM)
            xv = *(const float4*)(xT + t * 2048 + rg * 32 + rt * 16 + quad * 4);

        // ---- MFMA: gates = h @ W^T, 3-pass hi/lo ----
        floatx4 acc[4];
        #pragma unroll
        for (int nt = 0; nt < 4; ++nt) acc[nt] = (floatx4){0.f, 0.f, 0.f, 0.f};
        #pragma unroll
        for (int kt = 0; kt < 8; ++kt) {
            bf16x8 ah = *(const bf16x8*)(hhi_s + (rt * 8 + kt) * 512 + lane * 8);
            bf16x8 al = *(const bf16x8*)(hlo_s + (rt * 8 + kt) * 512 + lane * 8);
            #pragma unroll
            for (int nt = 0; nt < 4; ++nt) {
                bf16x8 bl = *(const bf16x8*)(wlo_s + ((uchw * 4 + nt) * 8 + kt) * 512 + lane * 8);
                acc[nt] = __builtin_amdgcn_mfma_f32_16x16x32_bf16(ah, bhi[nt][kt], acc[nt], 0, 0, 0);
                acc[nt] = __builtin_amdgcn_mfma_f32_16x16x32_bf16(al, bhi[nt][kt], acc[nt], 0, 0, 0);
                acc[nt] = __builtin_amdgcn_mfma_f32_16x16x32_bf16(ah, bl,          acc[nt], 0, 0, 0);
            }
        }

        // ---- gate exchange with lane^1 partner (even lane: unit A, odd: unit B) ----
        const bool odd = (lane & 1);
        floatx4 s0 = odd ? acc[0] : acc[2];
        floatx4 s1 = odd ? acc[1] : acc[3];
        floatx4 r0, r1;
        #pragma unroll
        for (int i = 0; i < 4; ++i) {
            r0[i] = __shfl_xor(s0[i], 1, 64);
            r1[i] = __shfl_xor(s1[i], 1, 64);
        }
        floatx4 gI = odd ? r0 : acc[0];
        floatx4 gG = odd ? r1 : acc[1];
        floatx4 gF = odd ? acc[2] : r0;
        floatx4 gO = odd ? acc[3] : r1;

        // ---- elementwise LSTM + LLC h store ----
        uint* hdst = hg + (size_t)(1u - par) * HG_PAR + (size_t)rg * 8192;
        const float xin[4] = {xv.x, xv.y, xv.z, xv.w};
        #pragma unroll
        for (int i = 0; i < 4; ++i) {
            const int m = quad * 4 + i;
            float inr = (t < WARM) ? xin[i] : (y_s[par * 32 + rt * 16 + m] + fcb0);
            float vi = gI[i] + bbg[0] + inr * wig[0];
            float vf = gF[i] + bbg[1] + inr * wig[1];
            float vg = gG[i] + bbg[2] + inr * wig[2];
            float vo = gO[i] + bbg[3] + inr * wig[3];
            float cn = fast_sig(vf) * c[i] + fast_sig(vi) * fast_tanh(vg);
            c[i] = cn;
            float h = fast_sig(vo) * fast_tanh(cn);
            short hi = f2bf(h);
            short lo = f2bf(h - bf2f(hi));
            store_llc32(hdst + ((size_t)(rt * 8 + ktu) * 64 + m + 16 * ksubu) * 8 + ju,
                        ((uint)(unsigned short)hi << 16) | (uint)(unsigned short)lo);
        }
        asm volatile("s_waitcnt vmcnt(0)" ::: "memory");   // h stores at LLC

        // ---- mini-barrier: all half-waves done -> flag++ ----
        if (lane == 0) atomicAdd(&mb[1], 1u);
        while (*(volatile uint*)&mb[1] < nbar) {}
        if (wl == 0 && lane == 0)
            __hip_atomic_fetch_add(barp, 1u, __ATOMIC_RELAXED, __HIP_MEMORY_SCOPE_AGENT);
    }
}

extern "C" void kernel_launch(void* const* d_in, const int* in_sizes, int n_in,
                              void* d_out, int out_size, void* d_ws, size_t ws_size,
                              hipStream_t stream) {
    const float* x    = (const float*)d_in[0];
    const float* h0   = (const float*)d_in[1];
    const float* c0   = (const float*)d_in[2];
    const float* W_ih = (const float*)d_in[3];
    const float* W_hh = (const float*)d_in[4];
    const float* b_ih = (const float*)d_in[5];
    const float* b_hh = (const float*)d_in[6];
    const float* fc_w = (const float*)d_in[7];
    const float* fc_b = (const float*)d_in[8];
    float* out = (float*)d_out;
    unsigned char* ws = (unsigned char*)d_ws;

    lstm_prep<<<2048, 256, 0, stream>>>(W_ih, W_hh, b_ih, b_hh, h0, x, ws);

    static int attr_set = 0;
    if (!attr_set) {
        (void)hipFuncSetAttribute((const void*)lstm_main,
                                  hipFuncAttributeMaxDynamicSharedMemorySize, LDS_BYTES);
        attr_set = 1;
    }
    void* args[] = {(void*)&c0, (void*)&ws, (void*)&fc_w, (void*)&fc_b, (void*)&out};
    (void)hipLaunchCooperativeKernel((const void*)lstm_main, dim3(256), dim3(512),
                                     args, LDS_BYTES, stream);
}